// Round 3
// baseline (584.459 us; speedup 1.0000x reference)
//
#include <hip/hip_runtime.h>

#define NN 100000
#define EE 1600000
#define CH 128
#define NG 512
#define OC 64

// coarse radix partition: 98 buckets of 1024 nodes; fixed-capacity staging cells
#define CSH 10
#define NCB 98
#define PBLK 256
#define PCHUNK 6250     // 256*6250 = 1.6M exactly
#define SCAP 128        // per (block,bucket) cell: mean 63.8 + 8 sigma

// workspace element offsets (4-byte units); total 110.4 MB
#define O_DINV   0
#define O_ROWS   100032   // 100001
#define O_CNT    200064   // 25088
#define O_PART   225152
#define O_OFFS   225280
#define O_START  225408   // 513
#define O_CSR    225984   // padded CSR, cap 2.50M words (sum pdeg <= 2.3M)
#define O_HS     2726016  // bf16 Hs slice-blocked: 8 x 100001 x 16 ush = 6400064 words
#define O_STG    9126080  // staging 3.21M words (dead after k_place)
#define O_WT1    9126080  // split W1: 32768 ushorts = 16384 words
#define O_WT2    9142464
#define O_A1     14800448 // bf16 A1 slice-blocked: 8 x 100000 x 16 ush = 6.4M words

// slice-blocked layout strides
#define HSL_US 1600016u   // ushorts per Hs slice (100001*16)
#define HSL_U32 800008u   // uints per Hs slice
#define ASL_US 1600000u   // ushorts per A1 slice (100000*16)
#define ASL_U32 800000u   // uints per A1 slice

typedef __attribute__((ext_vector_type(8))) short short8v;
typedef __attribute__((ext_vector_type(4))) float float4v;

static __device__ __forceinline__ unsigned short f2bf(float x) {
  unsigned u = __float_as_uint(x);
  return (unsigned short)((u + 0x7FFFu + ((u >> 16) & 1u)) >> 16);  // RNE
}
static __device__ __forceinline__ float bf2f(unsigned short h) {
  return __uint_as_float((unsigned)h << 16);
}
static __device__ __forceinline__ unsigned pack2(float a, float b) {
  return (unsigned)f2bf(a) | ((unsigned)f2bf(b) << 16);
}
static __device__ __forceinline__ float bflo(unsigned v) {
  return __uint_as_float(v << 16);
}
static __device__ __forceinline__ float bfhi(unsigned v) {
  return __uint_as_float(v & 0xFFFF0000u);
}

// LDS radix scatter: hist -> scan -> ordered LDS buffer -> contiguous run copies.
__global__ __launch_bounds__(1024) void k_part(const int* __restrict__ src,
                                               const int* __restrict__ dst,
                                               int* __restrict__ cnt,
                                               unsigned* __restrict__ stg) {
  __shared__ int hist[NCB];   // counts, then exclusive bases
  __shared__ int lcur[NCB];
  __shared__ unsigned lout[PCHUNK];
  int t = threadIdx.x;
  int e0 = blockIdx.x * PCHUNK;
  if (t < NCB) { hist[t] = 0; lcur[t] = 0; }
  __syncthreads();
  for (int e = e0 + t; e < e0 + PCHUNK; e += 1024)
    atomicAdd(&hist[dst[e] >> CSH], 1);
  __syncthreads();
  if (t == 0) {
    int s = 0;
    for (int i = 0; i < NCB; ++i) { int v = hist[i]; hist[i] = s; s += v; }
  }
  __syncthreads();
  for (int e = e0 + t; e < e0 + PCHUNK; e += 1024) {
    int d = dst[e];
    int b = d >> CSH;
    int p = hist[b] + atomicAdd(&lcur[b], 1);
    lout[p] = (unsigned)src[e] | ((unsigned)(d & 1023) << 17);
  }
  __syncthreads();
  int w = t >> 6, lane = t & 63;
  unsigned* mystg = stg + (size_t)blockIdx.x * NCB * SCAP;
  for (int b = w; b < NCB; b += 16) {
    int beg = hist[b];
    int end = (b == NCB - 1) ? PCHUNK : hist[b + 1];
    int n = min(end - beg, SCAP);
    for (int i = lane; i < n; i += 64) mystg[b * SCAP + i] = lout[beg + i];
    if (lane == 0) cnt[blockIdx.x * NCB + b] = n;
  }
}

// Per bucket: degree histogram, dinv (real deg), exclusive scan of PADDED deg.
__global__ __launch_bounds__(1024) void k_count(const unsigned* __restrict__ stg,
                                                const int* __restrict__ cnt,
                                                int* __restrict__ rows,
                                                int* __restrict__ part,
                                                float* __restrict__ dinv) {
  __shared__ int ldeg[1024];
  __shared__ int s[1024];
  int b = blockIdx.x;
  int t = threadIdx.x;
  int w = t >> 6, lane = t & 63;
  int gid = (b << CSH) + t;
  ldeg[t] = 0;
  __syncthreads();
  for (int blk = w; blk < PBLK; blk += 16) {
    int c = cnt[blk * NCB + b];
    const unsigned* p = stg + ((size_t)blk * NCB + b) * SCAP;
    for (int e = lane; e < c; e += 64) atomicAdd(&ldeg[p[e] >> 17], 1);
  }
  __syncthreads();
  int v = ldeg[t];
  if (gid < NN) dinv[gid] = rsqrtf((float)(v + 1));  // +1 self-loop (real deg)
  int pdeg = (v + 7) & ~7;                           // pad to x8 for aggregate
  s[t] = pdeg;
  __syncthreads();
  for (int off = 1; off < 1024; off <<= 1) {
    int u = (t >= off) ? s[t - off] : 0;
    __syncthreads();
    if (t >= off) s[t] += u;
    __syncthreads();
  }
  if (gid < NN) rows[gid] = s[t] - pdeg;    // bucket-local exclusive (padded)
  if (t == 1023) part[b] = s[t];            // bucket padded total
}

__global__ void k_scan_part(const int* __restrict__ part, int* __restrict__ offs) {
  __shared__ int s[128];
  int t = threadIdx.x;
  int v = (t < NCB) ? part[t] : 0;
  s[t] = v;
  __syncthreads();
  for (int off = 1; off < 128; off <<= 1) {
    int u = (t >= off) ? s[t - off] : 0;
    __syncthreads();
    if (t >= off) s[t] += u;
    __syncthreads();
  }
  if (t < NCB) offs[t] = s[t] - v;
}

// globalize rows + fused batch-starts. rows[NN] = total padded edges.
__global__ void k_scan_add(int* __restrict__ rows, const int* __restrict__ offs,
                           const int* __restrict__ part,
                           const int* __restrict__ batch, int* __restrict__ start) {
  int i = blockIdx.x * 256 + threadIdx.x;
  if (i >= NN) return;
  rows[i] += offs[i >> 10];
  if (i == 0) rows[NN] = offs[NCB - 1] + part[NCB - 1];
  int b = batch[i];
  int prev = (i == 0) ? -1 : batch[i - 1];
  for (int g = prev + 1; g <= b; ++g) start[g] = i;
  if (i == NN - 1)
    for (int g = b + 1; g <= NG; ++g) start[g] = NN;
}

// Per bucket: place srcs via LDS cursors; fill pad slots with dummy node NN.
__global__ __launch_bounds__(1024) void k_place(const unsigned* __restrict__ stg,
                                                const int* __restrict__ cnt,
                                                const int* __restrict__ rows,
                                                int* __restrict__ csr) {
  __shared__ int lrow[1024];
  __shared__ int lcur[1024];
  int b = blockIdx.x;
  int t = threadIdx.x;
  int w = t >> 6, lane = t & 63;
  int gid = (b << CSH) + t;
  lrow[t] = (gid < NN) ? rows[gid] : 0;
  lcur[t] = 0;
  __syncthreads();
  for (int blk = w; blk < PBLK; blk += 16) {
    int c = cnt[blk * NCB + b];
    const unsigned* p = stg + ((size_t)blk * NCB + b) * SCAP;
    for (int e = lane; e < c; e += 64) {
      unsigned x = p[e];
      int ld = x >> 17;
      int q = atomicAdd(&lcur[ld], 1);
      csr[lrow[ld] + q] = (int)(x & 0x1FFFFu);
    }
  }
  __syncthreads();
  int d = lcur[t];
  int pd = (d + 7) & ~7;
  int base = lrow[t];
  for (int i = d; i < pd; ++i) csr[base + i] = NN;  // dummy zero row
}

// split W1,W2 (fp32 [k][n]) into bf16 hi/lo, transposed to [n][k]; one launch.
__global__ void k_wsplit(const float* __restrict__ W1, const float* __restrict__ W2,
                         unsigned short* __restrict__ wt1,
                         unsigned short* __restrict__ wt2) {
  int id = blockIdx.x * 256 + threadIdx.x;   // 32768
  const float* W = (id < 16384) ? W1 : W2;
  unsigned short* wt = (id < 16384) ? wt1 : wt2;
  int i = id & 16383;
  int k = i >> 7, n = i & 127;
  float w = W[i];
  unsigned short h = f2bf(w);
  unsigned short l = f2bf(w - bf2f(h));
  wt[n * 128 + k] = h;
  wt[16384 + n * 128 + k] = l;
}

// Layer-1: Hsb(bf16, slice-blocked) = diag(dinv) * (X_fp32 @ W), split-bf16 MFMA.
__global__ __launch_bounds__(256) void k_gemm_mfma(
    const float* __restrict__ X, const unsigned short* __restrict__ wth,
    const unsigned short* __restrict__ wtl, const float* __restrict__ dinv,
    unsigned short* __restrict__ Hs) {
  __shared__ __align__(16) unsigned short sWh[64 * 136];  // [n][k] pad 136
  __shared__ __align__(16) unsigned short sWl[64 * 136];
  __shared__ __align__(16) unsigned short sXh[128 * 40];  // [row][k-chunk 32] pad 40
  __shared__ __align__(16) unsigned short sXl[128 * 40];

  const int t = threadIdx.x;
  const int w = t >> 6, lane = t & 63;
  const int quad = lane >> 4, lr = lane & 15;
  const int row0 = blockIdx.x * 128;
  const int col0 = blockIdx.y * 64;

  // zero the dummy row NN in every slice (read by k_aggregate pad slots)
  if (blockIdx.x == 0 && blockIdx.y == 0 && t < 64) {
    unsigned* Hu = (unsigned*)Hs;
    Hu[(size_t)(t >> 3) * HSL_U32 + (unsigned)NN * 8u + (t & 7)] = 0u;
  }

#pragma unroll
  for (int j = 0; j < 8; ++j) {
    int id = t + j * 256;
    int n = id >> 5, kk = (id & 31) * 4;
    *(ushort4*)&sWh[n * 136 + kk] = *(const ushort4*)&wth[(col0 + n) * 128 + kk];
    *(ushort4*)&sWl[n * 136 + kk] = *(const ushort4*)&wtl[(col0 + n) * 128 + kk];
  }

  float4v acc[2][4];
#pragma unroll
  for (int mi = 0; mi < 2; ++mi)
#pragma unroll
    for (int ni = 0; ni < 4; ++ni) acc[mi][ni] = (float4v){0.f, 0.f, 0.f, 0.f};

  for (int ks = 0; ks < 4; ++ks) {
    const int k0 = ks * 32;
    if (ks) __syncthreads();
#pragma unroll
    for (int i = 0; i < 4; ++i) {
      int row = i * 32 + (t >> 3);
      int seg = t & 7;
      int gr = row0 + row;
      float4 xv = {0.f, 0.f, 0.f, 0.f};
      if (gr < NN) xv = *(const float4*)&X[(size_t)gr * CH + k0 + seg * 4];
      ushort4 h, l;
      h.x = f2bf(xv.x); l.x = f2bf(xv.x - bf2f(h.x));
      h.y = f2bf(xv.y); l.y = f2bf(xv.y - bf2f(h.y));
      h.z = f2bf(xv.z); l.z = f2bf(xv.z - bf2f(h.z));
      h.w = f2bf(xv.w); l.w = f2bf(xv.w - bf2f(h.w));
      *(ushort4*)&sXh[row * 40 + seg * 4] = h;
      *(ushort4*)&sXl[row * 40 + seg * 4] = l;
    }
    __syncthreads();

    short8v ah[2], al[2];
#pragma unroll
    for (int mi = 0; mi < 2; ++mi) {
      int r = w * 32 + mi * 16 + lr;
      ah[mi] = *(const short8v*)&sXh[r * 40 + quad * 8];
      al[mi] = *(const short8v*)&sXl[r * 40 + quad * 8];
    }
#pragma unroll
    for (int ni = 0; ni < 4; ++ni) {
      int n = ni * 16 + lr;
      short8v bh = *(const short8v*)&sWh[n * 136 + k0 + quad * 8];
      short8v bl = *(const short8v*)&sWl[n * 136 + k0 + quad * 8];
#pragma unroll
      for (int mi = 0; mi < 2; ++mi) {
        acc[mi][ni] = __builtin_amdgcn_mfma_f32_16x16x32_bf16(ah[mi], bh, acc[mi][ni], 0, 0, 0);
        acc[mi][ni] = __builtin_amdgcn_mfma_f32_16x16x32_bf16(ah[mi], bl, acc[mi][ni], 0, 0, 0);
        acc[mi][ni] = __builtin_amdgcn_mfma_f32_16x16x32_bf16(al[mi], bh, acc[mi][ni], 0, 0, 0);
      }
    }
  }

#pragma unroll
  for (int mi = 0; mi < 2; ++mi) {
#pragma unroll
    for (int r = 0; r < 4; ++r) {
      int grow = row0 + w * 32 + mi * 16 + quad * 4 + r;
      if (grow < NN) {
        float d = dinv[grow];
#pragma unroll
        for (int ni = 0; ni < 4; ++ni)
          Hs[(size_t)(col0 / 16 + ni) * HSL_US + (size_t)grow * 16 + lr] =
              f2bf(d * acc[mi][ni][r]);
      }
    }
  }
}

// Layer-2: Hsb(bf16) = diag(dinv) * (A1b_bf16 @ W); A slice-blocked input.
__global__ __launch_bounds__(256) void k_gemm_bf(
    const unsigned short* __restrict__ A, const unsigned short* __restrict__ wth,
    const unsigned short* __restrict__ wtl, const float* __restrict__ dinv,
    unsigned short* __restrict__ Hs) {
  __shared__ __align__(16) unsigned short sWh[64 * 136];
  __shared__ __align__(16) unsigned short sWl[64 * 136];
  __shared__ __align__(16) unsigned short sA[128 * 40];

  const int t = threadIdx.x;
  const int w = t >> 6, lane = t & 63;
  const int quad = lane >> 4, lr = lane & 15;
  const int row0 = blockIdx.x * 128;
  const int col0 = blockIdx.y * 64;

  if (blockIdx.x == 0 && blockIdx.y == 0 && t < 64) {
    unsigned* Hu = (unsigned*)Hs;
    Hu[(size_t)(t >> 3) * HSL_U32 + (unsigned)NN * 8u + (t & 7)] = 0u;
  }

#pragma unroll
  for (int j = 0; j < 8; ++j) {
    int id = t + j * 256;
    int n = id >> 5, kk = (id & 31) * 4;
    *(ushort4*)&sWh[n * 136 + kk] = *(const ushort4*)&wth[(col0 + n) * 128 + kk];
    *(ushort4*)&sWl[n * 136 + kk] = *(const ushort4*)&wtl[(col0 + n) * 128 + kk];
  }

  float4v acc[2][4];
#pragma unroll
  for (int mi = 0; mi < 2; ++mi)
#pragma unroll
    for (int ni = 0; ni < 4; ++ni) acc[mi][ni] = (float4v){0.f, 0.f, 0.f, 0.f};

  for (int ks = 0; ks < 4; ++ks) {
    const int k0 = ks * 32;
    if (ks) __syncthreads();
    // stage A[row0..row0+127][k0..k0+31] from slice-blocked layout:
    // k-chunk 32 = slices 2*ks, 2*ks+1; 32 B contiguous per (node, slice).
    {
      int row = t >> 1, half = t & 1;
      int gr = row0 + row;
      uint4 v0 = {0u, 0u, 0u, 0u}, v1 = {0u, 0u, 0u, 0u};
      if (gr < NN) {
        const unsigned short* src =
            A + (size_t)(2 * ks + half) * ASL_US + (size_t)gr * 16;
        v0 = *(const uint4*)src;
        v1 = *(const uint4*)(src + 8);
      }
      *(uint4*)&sA[row * 40 + half * 16] = v0;
      *(uint4*)&sA[row * 40 + half * 16 + 8] = v1;
    }
    __syncthreads();

    short8v ah[2];
#pragma unroll
    for (int mi = 0; mi < 2; ++mi) {
      int r = w * 32 + mi * 16 + lr;
      ah[mi] = *(const short8v*)&sA[r * 40 + quad * 8];
    }
#pragma unroll
    for (int ni = 0; ni < 4; ++ni) {
      int n = ni * 16 + lr;
      short8v bh = *(const short8v*)&sWh[n * 136 + k0 + quad * 8];
      short8v bl = *(const short8v*)&sWl[n * 136 + k0 + quad * 8];
#pragma unroll
      for (int mi = 0; mi < 2; ++mi) {
        acc[mi][ni] = __builtin_amdgcn_mfma_f32_16x16x32_bf16(ah[mi], bh, acc[mi][ni], 0, 0, 0);
        acc[mi][ni] = __builtin_amdgcn_mfma_f32_16x16x32_bf16(ah[mi], bl, acc[mi][ni], 0, 0, 0);
      }
    }
  }

#pragma unroll
  for (int mi = 0; mi < 2; ++mi) {
#pragma unroll
    for (int r = 0; r < 4; ++r) {
      int grow = row0 + w * 32 + mi * 16 + quad * 4 + r;
      if (grow < NN) {
        float d = dinv[grow];
#pragma unroll
        for (int ni = 0; ni < 4; ++ni)
          Hs[(size_t)(col0 / 16 + ni) * HSL_US + (size_t)grow * 16 + lr] =
              f2bf(d * acc[mi][ni][r]);
      }
    }
  }
}

// out(bf16, slice-blocked) = relu(dinv*(Hsb self + sum Hsb[csr]) + b).
// 8 channel-slices of 16 ch (32 B/node); slice s pinned to XCD s via b&7 so the
// 3.2-MB slice becomes L2-resident on its XCD (gathers hit L2; fabric traffic =
// compulsory 3.2 MB/XCD + csr stream). Wave = 8 edge-slots x 8 lanes; each lane
// carries one uint (2 ch); butterfly-reduce slots; wave loops over 8 nodes.
__global__ __launch_bounds__(256) void k_aggregate(
    const unsigned* __restrict__ H, const int* __restrict__ rows,
    const int* __restrict__ csr, const float* __restrict__ dinv,
    const float* __restrict__ bias, unsigned* __restrict__ out) {
  unsigned b = blockIdx.x;
  unsigned s = b & 7u;                  // slice == presumed XCD
  unsigned nb = b >> 3;                 // node-block 0..3124 (32 nodes each)
  int lane = threadIdx.x & 63;
  int ss = lane >> 3;                   // edge slot 0..7
  unsigned ln = (unsigned)(lane & 7);   // uint within slice (2 channels)
  const unsigned* Hb = H + (size_t)s * HSL_U32 + ln;
  unsigned obase = s * ASL_U32 + ln;
  float2 bv = *(const float2*)&bias[(s * 8u + ln) * 2];
  int node0 = (int)(nb * 32) + (threadIdx.x >> 6) * 8;
  for (int node = node0; node < node0 + 8; ++node) {
    float a0 = 0.f, a1 = 0.f;
    int e0 = rows[node], e1 = rows[node + 1];  // padded, multiple of 8
    if (e1 > e0) {
      const int* cp = csr + e0 + ss;
      unsigned srcv = (unsigned)cp[0];
      cp += 8;
      for (int e = e0 + 8; e < e1; e += 8) {
        unsigned nsrc = (unsigned)cp[0];
        cp += 8;
        unsigned sv = Hb[srcv << 3];
        a0 += bflo(sv); a1 += bfhi(sv);
        srcv = nsrc;
      }
      unsigned sv = Hb[srcv << 3];
      a0 += bflo(sv); a1 += bfhi(sv);
    }
    // reduce the 8 edge-slots (lanes with equal ln)
    a0 += __shfl_xor(a0, 8);  a1 += __shfl_xor(a1, 8);
    a0 += __shfl_xor(a0, 16); a1 += __shfl_xor(a1, 16);
    a0 += __shfl_xor(a0, 32); a1 += __shfl_xor(a1, 32);
    // self-loop term
    unsigned sv = Hb[(unsigned)node << 3];
    a0 += bflo(sv); a1 += bfhi(sv);
    float d = dinv[node];
    float o0 = fmaxf(fmaf(d, a0, bv.x), 0.f);
    float o1 = fmaxf(fmaf(d, a1, bv.y), 0.f);
    if (lane < 8)
      out[obase + ((unsigned)node << 3)] = pack2(o0, o1);
  }
}

// Fused per-graph pipeline: segmented mean pool (slice-blocked bf16 A) -> MLP.
__global__ __launch_bounds__(256) void k_head(
    const unsigned short* __restrict__ A, const int* __restrict__ start,
    const float* __restrict__ W3, const float* __restrict__ b3,
    const float* __restrict__ W4, const float* __restrict__ b4,
    float* __restrict__ out) {
  __shared__ float pooled[128];
  __shared__ float part[128];
  __shared__ float g1[128];
  int g = blockIdx.x;
  int c = threadIdx.x & 127;
  int half = threadIdx.x >> 7;
  int s0 = start[g], s1 = start[g + 1];
  const unsigned short* Ac = A + (size_t)(c >> 4) * ASL_US + (c & 15);
  float sum = 0.f;
  for (int i = s0 + half; i < s1; i += 2)
    sum += bf2f(Ac[(size_t)i * 16]);
  if (half) part[c] = sum;
  __syncthreads();
  if (!half) {
    float n = fmaxf((float)(s1 - s0), 1.0f);
    pooled[c] = (sum + part[c]) / n;
  }
  __syncthreads();
  if (threadIdx.x < 128) {
    float acc = b3[c];
    for (int k = 0; k < 128; ++k) acc += pooled[k] * W3[k * CH + c];
    g1[c] = fmaxf(acc, 0.f);
  }
  __syncthreads();
  if (threadIdx.x < 64) {
    float acc = b4[threadIdx.x];
    for (int k = 0; k < 128; ++k) acc += g1[k] * W4[k * OC + threadIdx.x];
    out[(size_t)g * OC + threadIdx.x] = acc;
  }
}

extern "C" void kernel_launch(void* const* d_in, const int* in_sizes, int n_in,
                              void* d_out, int out_size, void* d_ws, size_t ws_size,
                              hipStream_t stream) {
  const float* X   = (const float*)d_in[0];
  const int* ei    = (const int*)d_in[1];
  const int* batch = (const int*)d_in[2];
  const float* W1  = (const float*)d_in[3];
  const float* b1  = (const float*)d_in[4];
  const float* W2  = (const float*)d_in[5];
  const float* b2  = (const float*)d_in[6];
  const float* W3  = (const float*)d_in[7];
  const float* b3  = (const float*)d_in[8];
  const float* W4  = (const float*)d_in[9];
  const float* b4  = (const float*)d_in[10];
  float* out = (float*)d_out;
  float* ws = (float*)d_ws;

  const int* src = ei;        // edge_index[0]
  const int* dst = ei + EE;   // edge_index[1]

  float* dinv = ws + O_DINV;
  int* rows   = (int*)(ws + O_ROWS);
  int* cnt    = (int*)(ws + O_CNT);
  int* part   = (int*)(ws + O_PART);
  int* offs   = (int*)(ws + O_OFFS);
  int* start  = (int*)(ws + O_START);
  int* csr    = (int*)(ws + O_CSR);
  unsigned short* Hs = (unsigned short*)(ws + O_HS);
  unsigned* stg = (unsigned*)(ws + O_STG);
  unsigned short* wt1 = (unsigned short*)(ws + O_WT1);
  unsigned short* wt2 = (unsigned short*)(ws + O_WT2);
  unsigned short* A1 = (unsigned short*)(ws + O_A1);

  k_part<<<PBLK, 1024, 0, stream>>>(src, dst, cnt, stg);
  k_count<<<NCB, 1024, 0, stream>>>(stg, cnt, rows, part, dinv);
  k_scan_part<<<1, 128, 0, stream>>>(part, offs);
  k_scan_add<<<(NN + 255) / 256, 256, 0, stream>>>(rows, offs, part, batch, start);
  k_place<<<NCB, 1024, 0, stream>>>(stg, cnt, rows, csr);
  // after k_place the staging region is dead; wt1/wt2 overwrite its start
  k_wsplit<<<128, 256, 0, stream>>>(W1, W2, wt1, wt2);

  dim3 ggrid((NN + 127) / 128, 2);
  // layer 1 (fp32 X input, 3-term split MFMA) -> slice-blocked Hs
  k_gemm_mfma<<<ggrid, 256, 0, stream>>>(X, wt1, wt1 + 16384, dinv, Hs);
  // aggregate: 8 slices x 3125 node-blocks (32 nodes/block), slice = b&7
  k_aggregate<<<25000, 256, 0, stream>>>((const unsigned*)Hs, rows, csr, dinv, b1, (unsigned*)A1);
  // layer 2 (slice-blocked bf16 A1 input, 2-term MFMA)
  k_gemm_bf<<<ggrid, 256, 0, stream>>>(A1, wt2, wt2 + 16384, dinv, Hs);
  k_aggregate<<<25000, 256, 0, stream>>>((const unsigned*)Hs, rows, csr, dinv, b2, (unsigned*)A1);

  k_head<<<NG, 256, 0, stream>>>(A1, start, W3, b3, W4, b4, out);
}

// Round 4
// 402.850 us; speedup vs baseline: 1.4508x; 1.4508x over previous
//
#include <hip/hip_runtime.h>

#define NN 100000
#define EE 1600000
#define CH 128
#define NG 512
#define OC 64

// coarse radix partition: 98 buckets of 1024 nodes; fixed-capacity staging cells
#define CSH 10
#define NCB 98
#define PBLK 256
#define PCHUNK 6250     // 256*6250 = 1.6M exactly
#define SCAP 128        // per (block,bucket) cell: mean 63.8 + 8 sigma

// workspace element offsets (4-byte units); total 110.4 MB
#define O_DINV   0
#define O_ROWS   100032   // 100001
#define O_CNT    200064   // 25088
#define O_PART   225152
#define O_OFFS   225280
#define O_START  225408   // 513
#define O_CSR    225984   // padded CSR, cap 2.50M words (sum pdeg <= 2.3M)
#define O_HS     2726016  // bf16 Hs slice-blocked: 8 x 100001 x 16 ush = 6400064 words
#define O_STG    9126080  // staging 3.21M words (dead after k_place)
#define O_WT1    9126080  // split W1: 32768 ushorts = 16384 words
#define O_WT2    9142464
#define O_A1     14800448 // bf16 A1 slice-blocked: 8 x 100000 x 16 ush = 6.4M words

// slice-blocked layout strides
#define HSL_US 1600016u   // ushorts per Hs slice (100001*16)
#define HSL_U32 800008u   // uints per Hs slice
#define ASL_US 1600000u   // ushorts per A1 slice (100000*16)
#define ASL_U32 800000u   // uints per A1 slice

typedef __attribute__((ext_vector_type(8))) short short8v;
typedef __attribute__((ext_vector_type(4))) float float4v;

static __device__ __forceinline__ unsigned short f2bf(float x) {
  unsigned u = __float_as_uint(x);
  return (unsigned short)((u + 0x7FFFu + ((u >> 16) & 1u)) >> 16);  // RNE
}
static __device__ __forceinline__ float bf2f(unsigned short h) {
  return __uint_as_float((unsigned)h << 16);
}
static __device__ __forceinline__ unsigned pack2(float a, float b) {
  return (unsigned)f2bf(a) | ((unsigned)f2bf(b) << 16);
}
static __device__ __forceinline__ float bflo(unsigned v) {
  return __uint_as_float(v << 16);
}
static __device__ __forceinline__ float bfhi(unsigned v) {
  return __uint_as_float(v & 0xFFFF0000u);
}

// LDS radix scatter: hist -> scan -> ordered LDS buffer -> contiguous run copies.
__global__ __launch_bounds__(1024) void k_part(const int* __restrict__ src,
                                               const int* __restrict__ dst,
                                               int* __restrict__ cnt,
                                               unsigned* __restrict__ stg) {
  __shared__ int hist[NCB];   // counts, then exclusive bases
  __shared__ int lcur[NCB];
  __shared__ unsigned lout[PCHUNK];
  int t = threadIdx.x;
  int e0 = blockIdx.x * PCHUNK;
  if (t < NCB) { hist[t] = 0; lcur[t] = 0; }
  __syncthreads();
  for (int e = e0 + t; e < e0 + PCHUNK; e += 1024)
    atomicAdd(&hist[dst[e] >> CSH], 1);
  __syncthreads();
  if (t == 0) {
    int s = 0;
    for (int i = 0; i < NCB; ++i) { int v = hist[i]; hist[i] = s; s += v; }
  }
  __syncthreads();
  for (int e = e0 + t; e < e0 + PCHUNK; e += 1024) {
    int d = dst[e];
    int b = d >> CSH;
    int p = hist[b] + atomicAdd(&lcur[b], 1);
    lout[p] = (unsigned)src[e] | ((unsigned)(d & 1023) << 17);
  }
  __syncthreads();
  int w = t >> 6, lane = t & 63;
  unsigned* mystg = stg + (size_t)blockIdx.x * NCB * SCAP;
  for (int b = w; b < NCB; b += 16) {
    int beg = hist[b];
    int end = (b == NCB - 1) ? PCHUNK : hist[b + 1];
    int n = min(end - beg, SCAP);
    for (int i = lane; i < n; i += 64) mystg[b * SCAP + i] = lout[beg + i];
    if (lane == 0) cnt[blockIdx.x * NCB + b] = n;
  }
}

// Per bucket: degree histogram, dinv (real deg), exclusive scan of PADDED deg.
__global__ __launch_bounds__(1024) void k_count(const unsigned* __restrict__ stg,
                                                const int* __restrict__ cnt,
                                                int* __restrict__ rows,
                                                int* __restrict__ part,
                                                float* __restrict__ dinv) {
  __shared__ int ldeg[1024];
  __shared__ int s[1024];
  int b = blockIdx.x;
  int t = threadIdx.x;
  int w = t >> 6, lane = t & 63;
  int gid = (b << CSH) + t;
  ldeg[t] = 0;
  __syncthreads();
  for (int blk = w; blk < PBLK; blk += 16) {
    int c = cnt[blk * NCB + b];
    const unsigned* p = stg + ((size_t)blk * NCB + b) * SCAP;
    for (int e = lane; e < c; e += 64) atomicAdd(&ldeg[p[e] >> 17], 1);
  }
  __syncthreads();
  int v = ldeg[t];
  if (gid < NN) dinv[gid] = rsqrtf((float)(v + 1));  // +1 self-loop (real deg)
  int pdeg = (v + 7) & ~7;                           // pad to x8 for aggregate
  s[t] = pdeg;
  __syncthreads();
  for (int off = 1; off < 1024; off <<= 1) {
    int u = (t >= off) ? s[t - off] : 0;
    __syncthreads();
    if (t >= off) s[t] += u;
    __syncthreads();
  }
  if (gid < NN) rows[gid] = s[t] - pdeg;    // bucket-local exclusive (padded)
  if (t == 1023) part[b] = s[t];            // bucket padded total
}

__global__ void k_scan_part(const int* __restrict__ part, int* __restrict__ offs) {
  __shared__ int s[128];
  int t = threadIdx.x;
  int v = (t < NCB) ? part[t] : 0;
  s[t] = v;
  __syncthreads();
  for (int off = 1; off < 128; off <<= 1) {
    int u = (t >= off) ? s[t - off] : 0;
    __syncthreads();
    if (t >= off) s[t] += u;
    __syncthreads();
  }
  if (t < NCB) offs[t] = s[t] - v;
}

// globalize rows + fused batch-starts. rows[NN] = total padded edges.
__global__ void k_scan_add(int* __restrict__ rows, const int* __restrict__ offs,
                           const int* __restrict__ part,
                           const int* __restrict__ batch, int* __restrict__ start) {
  int i = blockIdx.x * 256 + threadIdx.x;
  if (i >= NN) return;
  rows[i] += offs[i >> 10];
  if (i == 0) rows[NN] = offs[NCB - 1] + part[NCB - 1];
  int b = batch[i];
  int prev = (i == 0) ? -1 : batch[i - 1];
  for (int g = prev + 1; g <= b; ++g) start[g] = i;
  if (i == NN - 1)
    for (int g = b + 1; g <= NG; ++g) start[g] = NN;
}

// Per bucket: place srcs via LDS cursors; fill pad slots with dummy node NN.
__global__ __launch_bounds__(1024) void k_place(const unsigned* __restrict__ stg,
                                                const int* __restrict__ cnt,
                                                const int* __restrict__ rows,
                                                int* __restrict__ csr) {
  __shared__ int lrow[1024];
  __shared__ int lcur[1024];
  int b = blockIdx.x;
  int t = threadIdx.x;
  int w = t >> 6, lane = t & 63;
  int gid = (b << CSH) + t;
  lrow[t] = (gid < NN) ? rows[gid] : 0;
  lcur[t] = 0;
  __syncthreads();
  for (int blk = w; blk < PBLK; blk += 16) {
    int c = cnt[blk * NCB + b];
    const unsigned* p = stg + ((size_t)blk * NCB + b) * SCAP;
    for (int e = lane; e < c; e += 64) {
      unsigned x = p[e];
      int ld = x >> 17;
      int q = atomicAdd(&lcur[ld], 1);
      csr[lrow[ld] + q] = (int)(x & 0x1FFFFu);
    }
  }
  __syncthreads();
  int d = lcur[t];
  int pd = (d + 7) & ~7;
  int base = lrow[t];
  for (int i = d; i < pd; ++i) csr[base + i] = NN;  // dummy zero row
}

// split W1,W2 (fp32 [k][n]) into bf16 hi/lo, transposed to [n][k]; one launch.
__global__ void k_wsplit(const float* __restrict__ W1, const float* __restrict__ W2,
                         unsigned short* __restrict__ wt1,
                         unsigned short* __restrict__ wt2) {
  int id = blockIdx.x * 256 + threadIdx.x;   // 32768
  const float* W = (id < 16384) ? W1 : W2;
  unsigned short* wt = (id < 16384) ? wt1 : wt2;
  int i = id & 16383;
  int k = i >> 7, n = i & 127;
  float w = W[i];
  unsigned short h = f2bf(w);
  unsigned short l = f2bf(w - bf2f(h));
  wt[n * 128 + k] = h;
  wt[16384 + n * 128 + k] = l;
}

// Layer-1: Hsb(bf16, slice-blocked) = diag(dinv) * (X_fp32 @ W), split-bf16 MFMA.
__global__ __launch_bounds__(256) void k_gemm_mfma(
    const float* __restrict__ X, const unsigned short* __restrict__ wth,
    const unsigned short* __restrict__ wtl, const float* __restrict__ dinv,
    unsigned short* __restrict__ Hs) {
  __shared__ __align__(16) unsigned short sWh[64 * 136];  // [n][k] pad 136
  __shared__ __align__(16) unsigned short sWl[64 * 136];
  __shared__ __align__(16) unsigned short sXh[128 * 40];  // [row][k-chunk 32] pad 40
  __shared__ __align__(16) unsigned short sXl[128 * 40];

  const int t = threadIdx.x;
  const int w = t >> 6, lane = t & 63;
  const int quad = lane >> 4, lr = lane & 15;
  const int row0 = blockIdx.x * 128;
  const int col0 = blockIdx.y * 64;

  // zero the dummy row NN in every slice (read by k_aggregate pad slots)
  if (blockIdx.x == 0 && blockIdx.y == 0 && t < 64) {
    unsigned* Hu = (unsigned*)Hs;
    Hu[(size_t)(t >> 3) * HSL_U32 + (unsigned)NN * 8u + (t & 7)] = 0u;
  }

#pragma unroll
  for (int j = 0; j < 8; ++j) {
    int id = t + j * 256;
    int n = id >> 5, kk = (id & 31) * 4;
    *(ushort4*)&sWh[n * 136 + kk] = *(const ushort4*)&wth[(col0 + n) * 128 + kk];
    *(ushort4*)&sWl[n * 136 + kk] = *(const ushort4*)&wtl[(col0 + n) * 128 + kk];
  }

  float4v acc[2][4];
#pragma unroll
  for (int mi = 0; mi < 2; ++mi)
#pragma unroll
    for (int ni = 0; ni < 4; ++ni) acc[mi][ni] = (float4v){0.f, 0.f, 0.f, 0.f};

  for (int ks = 0; ks < 4; ++ks) {
    const int k0 = ks * 32;
    if (ks) __syncthreads();
#pragma unroll
    for (int i = 0; i < 4; ++i) {
      int row = i * 32 + (t >> 3);
      int seg = t & 7;
      int gr = row0 + row;
      float4 xv = {0.f, 0.f, 0.f, 0.f};
      if (gr < NN) xv = *(const float4*)&X[(size_t)gr * CH + k0 + seg * 4];
      ushort4 h, l;
      h.x = f2bf(xv.x); l.x = f2bf(xv.x - bf2f(h.x));
      h.y = f2bf(xv.y); l.y = f2bf(xv.y - bf2f(h.y));
      h.z = f2bf(xv.z); l.z = f2bf(xv.z - bf2f(h.z));
      h.w = f2bf(xv.w); l.w = f2bf(xv.w - bf2f(h.w));
      *(ushort4*)&sXh[row * 40 + seg * 4] = h;
      *(ushort4*)&sXl[row * 40 + seg * 4] = l;
    }
    __syncthreads();

    short8v ah[2], al[2];
#pragma unroll
    for (int mi = 0; mi < 2; ++mi) {
      int r = w * 32 + mi * 16 + lr;
      ah[mi] = *(const short8v*)&sXh[r * 40 + quad * 8];
      al[mi] = *(const short8v*)&sXl[r * 40 + quad * 8];
    }
#pragma unroll
    for (int ni = 0; ni < 4; ++ni) {
      int n = ni * 16 + lr;
      short8v bh = *(const short8v*)&sWh[n * 136 + k0 + quad * 8];
      short8v bl = *(const short8v*)&sWl[n * 136 + k0 + quad * 8];
#pragma unroll
      for (int mi = 0; mi < 2; ++mi) {
        acc[mi][ni] = __builtin_amdgcn_mfma_f32_16x16x32_bf16(ah[mi], bh, acc[mi][ni], 0, 0, 0);
        acc[mi][ni] = __builtin_amdgcn_mfma_f32_16x16x32_bf16(ah[mi], bl, acc[mi][ni], 0, 0, 0);
        acc[mi][ni] = __builtin_amdgcn_mfma_f32_16x16x32_bf16(al[mi], bh, acc[mi][ni], 0, 0, 0);
      }
    }
  }

#pragma unroll
  for (int mi = 0; mi < 2; ++mi) {
#pragma unroll
    for (int r = 0; r < 4; ++r) {
      int grow = row0 + w * 32 + mi * 16 + quad * 4 + r;
      if (grow < NN) {
        float d = dinv[grow];
#pragma unroll
        for (int ni = 0; ni < 4; ++ni)
          Hs[(size_t)(col0 / 16 + ni) * HSL_US + (size_t)grow * 16 + lr] =
              f2bf(d * acc[mi][ni][r]);
      }
    }
  }
}

// Layer-2: Hsb(bf16) = diag(dinv) * (A1b_bf16 @ W); A slice-blocked input.
__global__ __launch_bounds__(256) void k_gemm_bf(
    const unsigned short* __restrict__ A, const unsigned short* __restrict__ wth,
    const unsigned short* __restrict__ wtl, const float* __restrict__ dinv,
    unsigned short* __restrict__ Hs) {
  __shared__ __align__(16) unsigned short sWh[64 * 136];
  __shared__ __align__(16) unsigned short sWl[64 * 136];
  __shared__ __align__(16) unsigned short sA[128 * 40];

  const int t = threadIdx.x;
  const int w = t >> 6, lane = t & 63;
  const int quad = lane >> 4, lr = lane & 15;
  const int row0 = blockIdx.x * 128;
  const int col0 = blockIdx.y * 64;

  if (blockIdx.x == 0 && blockIdx.y == 0 && t < 64) {
    unsigned* Hu = (unsigned*)Hs;
    Hu[(size_t)(t >> 3) * HSL_U32 + (unsigned)NN * 8u + (t & 7)] = 0u;
  }

#pragma unroll
  for (int j = 0; j < 8; ++j) {
    int id = t + j * 256;
    int n = id >> 5, kk = (id & 31) * 4;
    *(ushort4*)&sWh[n * 136 + kk] = *(const ushort4*)&wth[(col0 + n) * 128 + kk];
    *(ushort4*)&sWl[n * 136 + kk] = *(const ushort4*)&wtl[(col0 + n) * 128 + kk];
  }

  float4v acc[2][4];
#pragma unroll
  for (int mi = 0; mi < 2; ++mi)
#pragma unroll
    for (int ni = 0; ni < 4; ++ni) acc[mi][ni] = (float4v){0.f, 0.f, 0.f, 0.f};

  for (int ks = 0; ks < 4; ++ks) {
    const int k0 = ks * 32;
    if (ks) __syncthreads();
    // stage A[row0..row0+127][k0..k0+31] from slice-blocked layout:
    // k-chunk 32 = slices 2*ks, 2*ks+1; 32 B contiguous per (node, slice).
    {
      int row = t >> 1, half = t & 1;
      int gr = row0 + row;
      uint4 v0 = {0u, 0u, 0u, 0u}, v1 = {0u, 0u, 0u, 0u};
      if (gr < NN) {
        const unsigned short* src =
            A + (size_t)(2 * ks + half) * ASL_US + (size_t)gr * 16;
        v0 = *(const uint4*)src;
        v1 = *(const uint4*)(src + 8);
      }
      *(uint4*)&sA[row * 40 + half * 16] = v0;
      *(uint4*)&sA[row * 40 + half * 16 + 8] = v1;
    }
    __syncthreads();

    short8v ah[2];
#pragma unroll
    for (int mi = 0; mi < 2; ++mi) {
      int r = w * 32 + mi * 16 + lr;
      ah[mi] = *(const short8v*)&sA[r * 40 + quad * 8];
    }
#pragma unroll
    for (int ni = 0; ni < 4; ++ni) {
      int n = ni * 16 + lr;
      short8v bh = *(const short8v*)&sWh[n * 136 + k0 + quad * 8];
      short8v bl = *(const short8v*)&sWl[n * 136 + k0 + quad * 8];
#pragma unroll
      for (int mi = 0; mi < 2; ++mi) {
        acc[mi][ni] = __builtin_amdgcn_mfma_f32_16x16x32_bf16(ah[mi], bh, acc[mi][ni], 0, 0, 0);
        acc[mi][ni] = __builtin_amdgcn_mfma_f32_16x16x32_bf16(ah[mi], bl, acc[mi][ni], 0, 0, 0);
      }
    }
  }

#pragma unroll
  for (int mi = 0; mi < 2; ++mi) {
#pragma unroll
    for (int r = 0; r < 4; ++r) {
      int grow = row0 + w * 32 + mi * 16 + quad * 4 + r;
      if (grow < NN) {
        float d = dinv[grow];
#pragma unroll
        for (int ni = 0; ni < 4; ++ni)
          Hs[(size_t)(col0 / 16 + ni) * HSL_US + (size_t)grow * 16 + lr] =
              f2bf(d * acc[mi][ni][r]);
      }
    }
  }
}

// out(bf16, slice-blocked) = relu(dinv*(Hsb self + sum Hsb[csr]) + b).
// Slice s pinned to XCD via b&7 (3.2-MB slice L2-resident; round-3 verified
// FETCH 190->64 MB). This round restores MLP: 8 node-slots IN PARALLEL per
// wave; slot = 2 edge-halves x 4 ch-lanes, each lane gathers uint2 (8 B);
// 4 rounds unrolled => 4 outstanding 8-B gathers/lane, 8 independent slots,
// one shfl_xor(4) per node total (vs 3 shfls/node + serial loads before).
__global__ __launch_bounds__(256) void k_aggregate(
    const unsigned* __restrict__ H, const int* __restrict__ rows,
    const int* __restrict__ csr, const float* __restrict__ dinv,
    const float* __restrict__ bias, unsigned* __restrict__ out) {
  unsigned b = blockIdx.x;
  unsigned s = b & 7u;                  // slice == presumed XCD
  unsigned nb = b >> 3;                 // node-block 0..3124 (32 nodes each)
  int lane = threadIdx.x & 63;
  int slot = lane >> 3;                 // node slot 0..7
  int ln = lane & 7;
  int eh = ln >> 2;                     // edge half 0/1
  unsigned lq = (unsigned)(ln & 3);     // uint2 index within 32-B slice row
  const uint2* Hb = (const uint2*)(H + (size_t)s * HSL_U32);
  int node = (int)(nb * 32) + (threadIdx.x >> 6) * 8 + slot;
  float a0 = 0.f, a1 = 0.f, a2 = 0.f, a3 = 0.f;
  int e0 = rows[node], e1 = rows[node + 1];  // padded, multiple of 8
  int n2 = (e1 - e0) >> 1;                   // rounds (2 edges each), mult of 4
  const int* cp = csr + e0 + eh;             // this half's edge stream
  for (int r = 0; r < n2; r += 4) {
    unsigned i0 = (unsigned)cp[0], i1 = (unsigned)cp[2];
    unsigned i2 = (unsigned)cp[4], i3 = (unsigned)cp[6];
    cp += 8;
    uint2 v0 = Hb[i0 * 4u + lq];
    uint2 v1 = Hb[i1 * 4u + lq];
    uint2 v2 = Hb[i2 * 4u + lq];
    uint2 v3 = Hb[i3 * 4u + lq];
    a0 += bflo(v0.x); a1 += bfhi(v0.x); a2 += bflo(v0.y); a3 += bfhi(v0.y);
    a0 += bflo(v1.x); a1 += bfhi(v1.x); a2 += bflo(v1.y); a3 += bfhi(v1.y);
    a0 += bflo(v2.x); a1 += bfhi(v2.x); a2 += bflo(v2.y); a3 += bfhi(v2.y);
    a0 += bflo(v3.x); a1 += bfhi(v3.x); a2 += bflo(v3.y); a3 += bfhi(v3.y);
  }
  // combine the two edge-halves (lanes ln and ln^4 share lq)
  a0 += __shfl_xor(a0, 4);
  a1 += __shfl_xor(a1, 4);
  a2 += __shfl_xor(a2, 4);
  a3 += __shfl_xor(a3, 4);
  // self-loop term (added once, after the half-combine)
  uint2 sv = Hb[(unsigned)node * 4u + lq];
  a0 += bflo(sv.x); a1 += bfhi(sv.x);
  a2 += bflo(sv.y); a3 += bfhi(sv.y);
  float d = dinv[node];
  float4 bv = *(const float4*)&bias[s * 16u + lq * 4u];
  float o0 = fmaxf(fmaf(d, a0, bv.x), 0.f);
  float o1 = fmaxf(fmaf(d, a1, bv.y), 0.f);
  float o2 = fmaxf(fmaf(d, a2, bv.z), 0.f);
  float o3 = fmaxf(fmaf(d, a3, bv.w), 0.f);
  if (eh == 0) {
    uint2* o = (uint2*)out + (size_t)s * (ASL_U32 / 2);
    o[(unsigned)node * 4u + lq] = make_uint2(pack2(o0, o1), pack2(o2, o3));
  }
}

// Fused per-graph pipeline: segmented mean pool (slice-blocked bf16 A) -> MLP.
__global__ __launch_bounds__(256) void k_head(
    const unsigned short* __restrict__ A, const int* __restrict__ start,
    const float* __restrict__ W3, const float* __restrict__ b3,
    const float* __restrict__ W4, const float* __restrict__ b4,
    float* __restrict__ out) {
  __shared__ float pooled[128];
  __shared__ float part[128];
  __shared__ float g1[128];
  int g = blockIdx.x;
  int c = threadIdx.x & 127;
  int half = threadIdx.x >> 7;
  int s0 = start[g], s1 = start[g + 1];
  const unsigned short* Ac = A + (size_t)(c >> 4) * ASL_US + (c & 15);
  float sum = 0.f;
  for (int i = s0 + half; i < s1; i += 2)
    sum += bf2f(Ac[(size_t)i * 16]);
  if (half) part[c] = sum;
  __syncthreads();
  if (!half) {
    float n = fmaxf((float)(s1 - s0), 1.0f);
    pooled[c] = (sum + part[c]) / n;
  }
  __syncthreads();
  if (threadIdx.x < 128) {
    float acc = b3[c];
    for (int k = 0; k < 128; ++k) acc += pooled[k] * W3[k * CH + c];
    g1[c] = fmaxf(acc, 0.f);
  }
  __syncthreads();
  if (threadIdx.x < 64) {
    float acc = b4[threadIdx.x];
    for (int k = 0; k < 128; ++k) acc += g1[k] * W4[k * OC + threadIdx.x];
    out[(size_t)g * OC + threadIdx.x] = acc;
  }
}

extern "C" void kernel_launch(void* const* d_in, const int* in_sizes, int n_in,
                              void* d_out, int out_size, void* d_ws, size_t ws_size,
                              hipStream_t stream) {
  const float* X   = (const float*)d_in[0];
  const int* ei    = (const int*)d_in[1];
  const int* batch = (const int*)d_in[2];
  const float* W1  = (const float*)d_in[3];
  const float* b1  = (const float*)d_in[4];
  const float* W2  = (const float*)d_in[5];
  const float* b2  = (const float*)d_in[6];
  const float* W3  = (const float*)d_in[7];
  const float* b3  = (const float*)d_in[8];
  const float* W4  = (const float*)d_in[9];
  const float* b4  = (const float*)d_in[10];
  float* out = (float*)d_out;
  float* ws = (float*)d_ws;

  const int* src = ei;        // edge_index[0]
  const int* dst = ei + EE;   // edge_index[1]

  float* dinv = ws + O_DINV;
  int* rows   = (int*)(ws + O_ROWS);
  int* cnt    = (int*)(ws + O_CNT);
  int* part   = (int*)(ws + O_PART);
  int* offs   = (int*)(ws + O_OFFS);
  int* start  = (int*)(ws + O_START);
  int* csr    = (int*)(ws + O_CSR);
  unsigned short* Hs = (unsigned short*)(ws + O_HS);
  unsigned* stg = (unsigned*)(ws + O_STG);
  unsigned short* wt1 = (unsigned short*)(ws + O_WT1);
  unsigned short* wt2 = (unsigned short*)(ws + O_WT2);
  unsigned short* A1 = (unsigned short*)(ws + O_A1);

  k_part<<<PBLK, 1024, 0, stream>>>(src, dst, cnt, stg);
  k_count<<<NCB, 1024, 0, stream>>>(stg, cnt, rows, part, dinv);
  k_scan_part<<<1, 128, 0, stream>>>(part, offs);
  k_scan_add<<<(NN + 255) / 256, 256, 0, stream>>>(rows, offs, part, batch, start);
  k_place<<<NCB, 1024, 0, stream>>>(stg, cnt, rows, csr);
  // after k_place the staging region is dead; wt1/wt2 overwrite its start
  k_wsplit<<<128, 256, 0, stream>>>(W1, W2, wt1, wt2);

  dim3 ggrid((NN + 127) / 128, 2);
  // layer 1 (fp32 X input, 3-term split MFMA) -> slice-blocked Hs
  k_gemm_mfma<<<ggrid, 256, 0, stream>>>(X, wt1, wt1 + 16384, dinv, Hs);
  // aggregate: 8 slices x 3125 node-blocks (32 nodes/block), slice = b&7
  k_aggregate<<<25000, 256, 0, stream>>>((const unsigned*)Hs, rows, csr, dinv, b1, (unsigned*)A1);
  // layer 2 (slice-blocked bf16 A1 input, 2-term MFMA)
  k_gemm_bf<<<ggrid, 256, 0, stream>>>(A1, wt2, wt2 + 16384, dinv, Hs);
  k_aggregate<<<25000, 256, 0, stream>>>((const unsigned*)Hs, rows, csr, dinv, b2, (unsigned*)A1);

  k_head<<<NG, 256, 0, stream>>>(A1, start, W3, b3, W4, b4, out);
}